// Round 8
// baseline (283.713 us; speedup 1.0000x reference)
//
#include <hip/hip_runtime.h>
#include <hip/hip_bf16.h>

// Problem constants (B=64, T=2048, D=512, U=512)
#define BB 64
#define TT 2048
#define DD 512
#define UU 512
#define MM (BB * TT)                 // 131072 rows
#define CTX_ELEMS (BB * DD)          // context region of d_out
#define ATTN_OFF  CTX_ELEMS          // attention region offset in d_out

typedef __bf16 bf16x8 __attribute__((ext_vector_type(8)));
typedef float  f32x4  __attribute__((ext_vector_type(4)));
typedef unsigned short u16x8 __attribute__((ext_vector_type(8)));
typedef unsigned int u32;

#define GLOBAL_AS __attribute__((address_space(1)))
#define LDS_AS    __attribute__((address_space(3)))

__device__ __forceinline__ unsigned short f2bf(float f) {
    union { float f; unsigned u; } x; x.f = f;
    unsigned r = x.u + 0x7fffu + ((x.u >> 16) & 1u);   // RNE
    return (unsigned short)(r >> 16);
}

__device__ __forceinline__ float tanh_fast(float x) {
    x = fminf(fmaxf(x, -10.f), 10.f);                  // avoid inf*0
    float e = __builtin_amdgcn_exp2f(x * 2.885390082f); // e^(2x)
    return (e - 1.0f) * __builtin_amdgcn_rcpf(e + 1.0f);
}

// ---------------------------------------------------------------------------
// Kernel 1: W1 [D][U] f32 -> W1T bf16, PRE-SWIZZLED layout for k_score:
//   gy = u>>7, n = u&127, kt = d>>6, kc8 = (d&63)>>3, e = d&7
//   byte off = gy*131072 + kt*16384 + kc8*2048 + ((n*16) ^ (kc8<<4))
// gload_lds copies linearly; k_score's frag reads apply the same XOR
// (both-sides swizzle rule). Per (gy,kt): contiguous 16 KB slab.
// ---------------------------------------------------------------------------
__global__ void k_w1t(const float* __restrict__ W1, unsigned short* __restrict__ W1T) {
    int gid = blockIdx.x * 256 + threadIdx.x;   // 32768 threads
    int u  = gid & 511;
    int dc = gid >> 9;                          // d-chunk of 8, 0..63
    int d0 = dc * 8;
    u16x8 pk;
    #pragma unroll
    for (int e = 0; e < 8; ++e)
        pk[e] = f2bf(W1[(size_t)(d0 + e) * UU + u]);
    int gy = u >> 7, n = u & 127;
    int kt = dc >> 3, kc8 = dc & 7;
    size_t off = (size_t)gy * 131072 + (size_t)kt * 16384 + kc8 * 2048
               + ((n * 16) ^ (kc8 << 4));
    *(u16x8*)((char*)W1T + off) = pk;
}

// ---------------------------------------------------------------------------
// Kernel 2: phc[b][u] = b1[u] + b2[u] + hidden[b,:] @ W2[:,u]
// ---------------------------------------------------------------------------
__global__ void k_phc(const float* __restrict__ hidden, const float* __restrict__ W2,
                      const float* __restrict__ b1, const float* __restrict__ b2,
                      float* __restrict__ phc) {
    const int b = blockIdx.x;
    const int u = threadIdx.x;         // 512 threads
    const float* h = hidden + (size_t)b * DD;
    float acc = b1[u] + b2[u];
    #pragma unroll 8
    for (int d = 0; d < DD; ++d)
        acc += h[d] * W2[(size_t)d * UU + u];
    phc[(size_t)b * UU + u] = acc;
}

// ---------------------------------------------------------------------------
// Kernel 3: partial-score GEMM. R2's multi-block 2-phase regime (best: 160us)
// with BK=64 (half the barrier events) and B never on the critical path.
// Tile BM=128 x BN=128 x BK=64; 256 threads = 4 waves (2x2 of 64x64).
// LDS 49 KB -> 3 blocks/CU (cross-block overlap is the latency hider).
//   sA: 16 KB single buf [kc8][row128][8e] bf16, XOR kc8<<4 swizzle
//   sB: 2 x 16 KB dbuf, same layout (pre-swizzled by k_w1t)
// Step kt: {issue A(kt+1)->regs, B(kt+1)->gload_lds(buf^1)} -> kk-loop
// (32 MFMA) -> BAR1 -> vmcnt(4) -> cvt+write A(kt+1) -> vmcnt(0) -> BAR2.
// A window = kk-loop; B window = full step (~free, L2-hot).
// Grid 4096 = 1024 mt x 4 gy, XCD-grouped (FETCH=1x verified R5/R7).
// ---------------------------------------------------------------------------
__launch_bounds__(256, 3)
__global__ void k_score(const float* __restrict__ feat,
                        const unsigned short* __restrict__ W1T,
                        const float* __restrict__ phc,
                        const float* __restrict__ V,
                        float* __restrict__ part) {
    __shared__ __align__(16) unsigned short sA[8 * 128 * 8];      // 16 KB
    __shared__ __align__(16) unsigned short sB[2][8 * 128 * 8];   // 32 KB
    __shared__ float sRed[4][64];

    const int tid   = threadIdx.x;
    const int lane  = tid & 63;
    const int w     = tid >> 6;               // wave 0..3
    const int wm    = w >> 1, wc = w & 1;     // 2M x 2N
    const int rlane = lane & 15;

    // XCD-aware decomposition (R2-proven)
    const int rb  = blockIdx.x;
    const int xcd = rb & 7;
    const int uu  = rb >> 3;
    const int gy  = uu & 3;
    const int gx  = xcd * 128 + (uu >> 2);
    const int m0  = gx * 128;
    const int b   = m0 >> 11;

    const char* bsl = (const char*)W1T + (size_t)gy * 131072;

    // A staging: thread covers row_s = tid>>1 (0..127), k-half h_s = tid&1
    const int row_s = tid >> 1;
    const int h_s   = tid & 1;
    const char* fA = (const char*)feat +
        ((size_t)(m0 + row_s) * 512 + (size_t)h_s * 32) * 4;

    // epilogue constants
    float pc[4], vv[4];
    #pragma unroll
    for (int ns = 0; ns < 4; ++ns) {
        int ug = gy * 128 + wc * 64 + ns * 16 + rlane;
        pc[ns] = phc[(size_t)b * UU + ug];
        vv[ns] = V[ug];
    }

    f32x4 rS[8];
    f32x4 acc[4][4];
    #pragma unroll
    for (int i = 0; i < 4; ++i)
        #pragma unroll
        for (int j = 0; j < 4; ++j)
            acc[i][j] = (f32x4){0.f, 0.f, 0.f, 0.f};

#define ISSUE_A(kt_) do {                                                     \
    _Pragma("unroll")                                                         \
    for (int q_ = 0; q_ < 8; ++q_)                                            \
        rS[q_] = *(const f32x4*)(fA + (kt_) * 256 + q_ * 16); } while (0)

#define ISSUE_B(kt_) do {                                                     \
    _Pragma("unroll")                                                         \
    for (int p_ = 0; p_ < 4; ++p_) {                                          \
        const char* src_ = bsl + (size_t)(kt_) * 16384 + p_ * 4096 + tid * 16;\
        char* dst_ = (char*)&sB[(kt_) & 1][0] + p_ * 4096 + (tid & ~63) * 16; \
        __builtin_amdgcn_global_load_lds((const GLOBAL_AS u32*)src_,          \
                                         (LDS_AS u32*)dst_, 16, 0, 0);        \
    } } while (0)

#define WRITE_A() do {                                                        \
    _Pragma("unroll")                                                         \
    for (int j_ = 0; j_ < 4; ++j_) {                                          \
        bf16x8 q_;                                                            \
        _Pragma("unroll")                                                     \
        for (int e_ = 0; e_ < 4; ++e_) {                                      \
            q_[e_]     = (__bf16)rS[2 * j_][e_];                              \
            q_[4 + e_] = (__bf16)rS[2 * j_ + 1][e_];                          \
        }                                                                     \
        int kc8_ = 4 * h_s + j_;                                              \
        *(bf16x8*)((char*)sA + kc8_ * 2048 + ((row_s * 16) ^ (kc8_ << 4))) = q_; \
    } } while (0)

#define DO_C(c_, cb_) do {                                                    \
    const int kc8_ = (c_) * 4 + (lane >> 4);                                  \
    const int xr_  = kc8_ << 4;                                               \
    bf16x8 af_[4], bf_[4];                                                    \
    _Pragma("unroll")                                                         \
    for (int ms_ = 0; ms_ < 4; ++ms_)                                         \
        af_[ms_] = *(const bf16x8*)((const char*)sA + kc8_ * 2048 +           \
                   (((wm * 64 + ms_ * 16 + rlane) * 16) ^ xr_));              \
    _Pragma("unroll")                                                         \
    for (int ns_ = 0; ns_ < 4; ++ns_)                                         \
        bf_[ns_] = *(const bf16x8*)((const char*)&sB[cb_][0] + kc8_ * 2048 +  \
                   (((wc * 64 + ns_ * 16 + rlane) * 16) ^ xr_));              \
    _Pragma("unroll")                                                         \
    for (int ms_ = 0; ms_ < 4; ++ms_)                                         \
        _Pragma("unroll")                                                     \
        for (int ns_ = 0; ns_ < 4; ++ns_)                                     \
            acc[ms_][ns_] = __builtin_amdgcn_mfma_f32_16x16x32_bf16(          \
                af_[ms_], bf_[ns_], acc[ms_][ns_], 0, 0, 0); } while (0)

#define STEP(kt_) do {                                                        \
    if ((kt_) < 7) {                                                          \
        ISSUE_A((kt_) + 1); ISSUE_B((kt_) + 1);                               \
        __builtin_amdgcn_sched_barrier(0);                                    \
    }                                                                         \
    DO_C(0, (kt_) & 1); DO_C(1, (kt_) & 1);                                   \
    asm volatile("s_waitcnt lgkmcnt(0)" ::: "memory");                        \
    __builtin_amdgcn_s_barrier();                                             \
    if ((kt_) < 7) {                                                          \
        asm volatile("s_waitcnt vmcnt(4)" ::: "memory");                      \
        WRITE_A();                                                            \
        asm volatile("s_waitcnt vmcnt(0)" ::: "memory");                      \
        asm volatile("s_waitcnt lgkmcnt(0)" ::: "memory");                    \
        __builtin_amdgcn_s_barrier();                                         \
    } } while (0)

    // ---- prologue: tile 0 ----
    ISSUE_A(0); ISSUE_B(0);
    __builtin_amdgcn_sched_barrier(0);
    asm volatile("s_waitcnt vmcnt(4)" ::: "memory");   // A(0) landed (8 oldest)
    WRITE_A();
    asm volatile("s_waitcnt vmcnt(0)" ::: "memory");   // B(0) in sB[0]
    asm volatile("s_waitcnt lgkmcnt(0)" ::: "memory");
    __builtin_amdgcn_s_barrier();

    STEP(0); STEP(1); STEP(2); STEP(3);
    STEP(4); STEP(5); STEP(6); STEP(7);

#undef STEP
#undef DO_C
#undef WRITE_A
#undef ISSUE_B
#undef ISSUE_A

    // --- epilogue: partial score over this block's 128 n-cols ---
    float pr[4][4];
    #pragma unroll
    for (int ms = 0; ms < 4; ++ms)
        #pragma unroll
        for (int rg = 0; rg < 4; ++rg) {
            float s = 0.f;
            #pragma unroll
            for (int ns = 0; ns < 4; ++ns)
                s += tanh_fast(acc[ms][ns][rg] + pc[ns]) * vv[ns];
            pr[ms][rg] = s;
        }
    #pragma unroll
    for (int off = 1; off < 16; off <<= 1)
        #pragma unroll
        for (int ms = 0; ms < 4; ++ms)
            #pragma unroll
            for (int rg = 0; rg < 4; ++rg)
                pr[ms][rg] += __shfl_xor(pr[ms][rg], off, 64);
    if ((lane & 15) == 0) {
        int rowg = lane >> 4;
        #pragma unroll
        for (int ms = 0; ms < 4; ++ms)
            #pragma unroll
            for (int rg = 0; rg < 4; ++rg)
                sRed[w][ms * 16 + rowg * 4 + rg] = pr[ms][rg];
    }
    __syncthreads();
    if (tid < 128) {
        int wrx = tid >> 6, ml = tid & 63;
        float v = sRed[2 * wrx][ml] + sRed[2 * wrx + 1][ml];
        part[(size_t)gy * MM + m0 + tid] = v;
    }
}

// ---------------------------------------------------------------------------
// Kernel 4: sum 4 partials -> softmax over T -> d_out attn region.
// ---------------------------------------------------------------------------
__global__ void k_softmax(const float* __restrict__ part, float* __restrict__ dout) {
    const int b = blockIdx.x, tid = threadIdx.x;   // 256 threads
    float* sc = dout + ATTN_OFF + (size_t)b * TT;
    float v[8];
    float mx = -3.4e38f;
    #pragma unroll
    for (int i = 0; i < 8; ++i) {
        int t = tid + 256 * i;
        size_t idx = (size_t)b * TT + t;
        v[i] = part[idx] + part[MM + idx] + part[2 * MM + idx] + part[3 * MM + idx];
        mx = fmaxf(mx, v[i]);
    }
    __shared__ float red[256];
    red[tid] = mx; __syncthreads();
    for (int s = 128; s >= 1; s >>= 1) {
        if (tid < s) red[tid] = fmaxf(red[tid], red[tid + s]);
        __syncthreads();
    }
    mx = red[0]; __syncthreads();
    float sum = 0.f;
    #pragma unroll
    for (int i = 0; i < 8; ++i) { v[i] = __expf(v[i] - mx); sum += v[i]; }
    red[tid] = sum; __syncthreads();
    for (int s = 128; s >= 1; s >>= 1) {
        if (tid < s) red[tid] += red[tid + s];
        __syncthreads();
    }
    float inv = 1.0f / red[0];
    #pragma unroll
    for (int i = 0; i < 8; ++i) sc[tid + 256 * i] = v[i] * inv;
}

// ---------------------------------------------------------------------------
// Kernel 5: context[b][d] = sum_t w[b][t] * feat[b][t][d]
// grid (64, 8); 256 threads = 16 d-quads (float4) x 16 t-subgroups.
// ---------------------------------------------------------------------------
__global__ void k_context(const float* __restrict__ feat, float* __restrict__ dout) {
    const int b = blockIdx.x, dc = blockIdx.y;
    const int dq = threadIdx.x & 15;          // float4 lane
    const int ty = threadIdx.x >> 4;          // 0..15
    const int d = dc * 64 + dq * 4;
    const float* wgt = dout + ATTN_OFF + (size_t)b * TT;
    const float* f = feat + (size_t)b * TT * DD + d;
    float4 acc = {0.f, 0.f, 0.f, 0.f};
    #pragma unroll 4
    for (int i = 0; i < TT / 16; ++i) {
        int t = i * 16 + ty;
        float wv = wgt[t];
        float4 fv = *(const float4*)(f + (size_t)t * DD);
        acc.x += wv * fv.x; acc.y += wv * fv.y;
        acc.z += wv * fv.z; acc.w += wv * fv.w;
    }
    __shared__ float4 red[16][16];
    red[ty][dq] = acc; __syncthreads();
    if (ty == 0) {
        float4 s = red[0][dq];
        #pragma unroll
        for (int k = 1; k < 16; ++k) {
            float4 r = red[k][dq];
            s.x += r.x; s.y += r.y; s.z += r.z; s.w += r.w;
        }
        *(float4*)(dout + (size_t)b * DD + d) = s;
    }
}

// ---------------------------------------------------------------------------
extern "C" void kernel_launch(void* const* d_in, const int* in_sizes, int n_in,
                              void* d_out, int out_size, void* d_ws, size_t ws_size,
                              hipStream_t stream) {
    (void)in_sizes; (void)n_in; (void)out_size; (void)ws_size;
    const float* feat   = (const float*)d_in[0];
    const float* hidden = (const float*)d_in[1];
    const float* W1     = (const float*)d_in[2];
    const float* b1     = (const float*)d_in[3];
    const float* W2     = (const float*)d_in[4];
    const float* b2     = (const float*)d_in[5];
    const float* V      = (const float*)d_in[6];
    // d_in[7] = bV : softmax-invariant constant, unused.

    // ws layout: [0,512K) W1T bf16; [512K,640K) phc f32; [640K,640K+2M) partials
    unsigned short* W1T = (unsigned short*)d_ws;
    float* phc  = (float*)((char*)d_ws + 512 * 1024);
    float* part = (float*)((char*)d_ws + 640 * 1024);
    float* out  = (float*)d_out;

    hipLaunchKernelGGL(k_w1t,     dim3(128),    dim3(256), 0, stream, W1, W1T);
    hipLaunchKernelGGL(k_phc,     dim3(64),     dim3(512), 0, stream, hidden, W2, b1, b2, phc);
    hipLaunchKernelGGL(k_score,   dim3(4096),   dim3(256), 0, stream, feat, W1T, phc, V, part);
    hipLaunchKernelGGL(k_softmax, dim3(64),     dim3(256), 0, stream, part, out);
    hipLaunchKernelGGL(k_context, dim3(64, 8),  dim3(256), 0, stream, feat, out);
}

// Round 10
// 216.405 us; speedup vs baseline: 1.3110x; 1.3110x over previous
//
#include <hip/hip_runtime.h>
#include <hip/hip_bf16.h>

// Problem constants (B=64, T=2048, D=512, U=512)
#define BB 64
#define TT 2048
#define DD 512
#define UU 512
#define MM (BB * TT)                 // 131072 rows
#define CTX_ELEMS (BB * DD)          // context region of d_out
#define ATTN_OFF  CTX_ELEMS          // attention region offset in d_out

typedef __bf16 bf16x8 __attribute__((ext_vector_type(8)));
typedef float  f32x4  __attribute__((ext_vector_type(4)));
typedef unsigned short u16x8 __attribute__((ext_vector_type(8)));
typedef unsigned int u32;

#define GLOBAL_AS __attribute__((address_space(1)))
#define LDS_AS    __attribute__((address_space(3)))

__device__ __forceinline__ unsigned short f2bf(float f) {
    union { float f; unsigned u; } x; x.f = f;
    unsigned r = x.u + 0x7fffu + ((x.u >> 16) & 1u);   // RNE
    return (unsigned short)(r >> 16);
}

__device__ __forceinline__ float tanh_fast(float x) {
    x = fminf(fmaxf(x, -10.f), 10.f);                  // avoid inf*0
    float e = __builtin_amdgcn_exp2f(x * 2.885390082f); // e^(2x)
    return (e - 1.0f) * __builtin_amdgcn_rcpf(e + 1.0f);
}

// ---------------------------------------------------------------------------
// Kernel 1: W1 [D][U] f32 -> W1T bf16, XOR-swizzled BK=32 tile layout:
//   gy=u>>7, n=u&127, kt32=d>>5, kc=(d&31)>>3, e=d&7
//   byte off = gy*131072 + kt32*8192 + kc*2048 + ((n*16) ^ (kc<<4))
// Per (gy,kt32): contiguous 8 KB slab -> linear gload_lds staging in k_score;
// frag reads apply the same XOR (both-sides rule).
// ---------------------------------------------------------------------------
__global__ void k_w1t(const float* __restrict__ W1, unsigned short* __restrict__ W1T) {
    int gid = blockIdx.x * 256 + threadIdx.x;   // 32768 threads
    int u  = gid & 511;
    int dc = gid >> 9;                          // d-chunk of 8, 0..63
    int d0 = dc * 8;
    u16x8 pk;
    #pragma unroll
    for (int e = 0; e < 8; ++e)
        pk[e] = f2bf(W1[(size_t)(d0 + e) * UU + u]);
    int gy = u >> 7, n = u & 127;
    int kt32 = dc >> 2, kc = dc & 3;
    size_t off = (size_t)gy * 131072 + (size_t)kt32 * 8192 + kc * 2048
               + ((n * 16) ^ (kc << 4));
    *(u16x8*)((char*)W1T + off) = pk;
}

// ---------------------------------------------------------------------------
// Kernel 2: phc[b][u] = b1[u] + b2[u] + hidden[b,:] @ W2[:,u]
// ---------------------------------------------------------------------------
__global__ void k_phc(const float* __restrict__ hidden, const float* __restrict__ W2,
                      const float* __restrict__ b1, const float* __restrict__ b2,
                      float* __restrict__ phc) {
    const int b = blockIdx.x;
    const int u = threadIdx.x;         // 512 threads
    const float* h = hidden + (size_t)b * DD;
    float acc = b1[u] + b2[u];
    #pragma unroll 8
    for (int d = 0; d < DD; ++d)
        acc += h[d] * W2[(size_t)d * UU + u];
    phc[(size_t)b * UU + u] = acc;
}

// ---------------------------------------------------------------------------
// Kernel 3: partial-score GEMM, ALL-gload_lds pipeline (zero reg staging,
// zero ds_writes, ONE barrier/epoch, counted vmcnt). R9 RACE FIX: next-tile
// loads are issued AFTER the epoch barrier (the barrier proves epoch t-1's
// readers of the target slots are done; issuing before it raced).
// BM=128 x BN=128 x BK=32; 256 thr = 4 waves (2x2 of 64x64); 16 epochs.
//  - A: f32 tiles gload_lds'd into a DEPTH-3 LDS ring (48 KB), issued 2
//    epochs ahead. Content XOR-swizzled by permuting the per-lane GLOBAL
//    source (LDS dest stays linear, m173). f32->bf16 cvt at frag-read time.
//  - B: bf16 pre-swizzled tiles (k_w1t), depth-2 ring, issued 1 ahead.
//  - Epoch t: vmcnt(4) [retires A(t),B(t); keeps A(t+1)] -> barrier ->
//    issue B(t+1),A(t+2) -> compute(t). E14 issues B15 only; E15 vmcnt(0).
// LDS 65 KB -> 2 blocks/CU (cross-block overlap hides residual latency).
// Grid 4096 = 1024 gx x 4 gy, XCD-grouped (FETCH=1x verified R5-R8).
// pc/vv loads live in the epilogue so they never enter the vmcnt ledger.
// ---------------------------------------------------------------------------
__launch_bounds__(256, 2)
__global__ void k_score(const float* __restrict__ feat,
                        const unsigned short* __restrict__ W1T,
                        const float* __restrict__ phc,
                        const float* __restrict__ V,
                        float* __restrict__ part) {
    __shared__ __align__(16) char ringA[3][16384];   // 48 KB, f32 tiles
    __shared__ __align__(16) char ringB[2][8192];    // 16 KB, bf16 tiles
    __shared__ float sRed[4][64];

    const int tid   = threadIdx.x;
    const int lane  = tid & 63;
    const int w     = tid >> 6;               // wave 0..3
    const int wm    = w >> 1, wc = w & 1;     // 2M x 2N
    const int rl    = lane & 15;
    const int kcl   = lane >> 4;              // 0..3

    // XCD-aware decomposition (R2-proven)
    const int rb  = blockIdx.x;
    const int xcd = rb & 7;
    const int uu  = rb >> 3;
    const int gy  = uu & 3;
    const int gx  = xcd * 128 + (uu >> 2);
    const int m0  = gx * 128;
    const int b   = m0 >> 11;

    const char* fb  = (const char*)feat + (size_t)m0 * 2048;
    const char* bsl = (const char*)W1T + (size_t)gy * 131072;

    // A staging source permutation (content-swizzle with linear LDS dest):
    // LDS byte L = p*4096 + tid*16 holds feat[row][kbyte], row = L>>7,
    // kbyte = (L&127) ^ ((row&7)<<4).
    const int arow = tid >> 3;                                  // 0..31
    const int axor = (((tid & 7) ^ ((tid >> 3) & 7)) << 4);

    f32x4 acc[4][4];
    #pragma unroll
    for (int i = 0; i < 4; ++i)
        #pragma unroll
        for (int j = 0; j < 4; ++j)
            acc[i][j] = (f32x4){0.f, 0.f, 0.f, 0.f};

#define VMW(N)  asm volatile("s_waitcnt vmcnt(" #N ")" ::: "memory")

#define ISSUE_A(kt_, s_) do {                                                  \
    _Pragma("unroll")                                                          \
    for (int p_ = 0; p_ < 4; ++p_) {                                           \
        const char* src_ = fb + (size_t)(p_ * 32 + arow) * 2048 +              \
                           (kt_) * 128 + axor;                                 \
        char* dst_ = (char*)&ringA[s_][0] + p_ * 4096 + (tid & ~63) * 16;      \
        __builtin_amdgcn_global_load_lds((const GLOBAL_AS u32*)src_,           \
                                         (LDS_AS u32*)dst_, 16, 0, 0);         \
    } } while (0)

#define ISSUE_B(kt_, s_) do {                                                  \
    _Pragma("unroll")                                                          \
    for (int p_ = 0; p_ < 2; ++p_) {                                           \
        const char* src_ = bsl + (size_t)(kt_) * 8192 + p_ * 4096 + tid * 16;  \
        char* dst_ = (char*)&ringB[s_][0] + p_ * 4096 + (tid & ~63) * 16;      \
        __builtin_amdgcn_global_load_lds((const GLOBAL_AS u32*)src_,           \
                                         (LDS_AS u32*)dst_, 16, 0, 0);         \
    } } while (0)

#define COMPUTE(kt_) do {                                                      \
    const char* aS_ = &ringA[(kt_) % 3][0];                                    \
    const char* bS_ = &ringB[(kt_) & 1][0];                                    \
    bf16x8 af_[4], bf_[4];                                                     \
    _Pragma("unroll")                                                          \
    for (int ms_ = 0; ms_ < 4; ++ms_) {                                        \
        int row_ = wm * 64 + ms_ * 16 + rl;                                    \
        int off_ = row_ * 128 + ((kcl * 32) ^ ((row_ & 7) << 4));              \
        f32x4 lo_ = *(const f32x4*)(aS_ + off_);                               \
        f32x4 hi_ = *(const f32x4*)(aS_ + (off_ ^ 16));                        \
        _Pragma("unroll")                                                      \
        for (int j_ = 0; j_ < 4; ++j_) {                                       \
            af_[ms_][j_]     = (__bf16)lo_[j_];                                \
            af_[ms_][4 + j_] = (__bf16)hi_[j_];                                \
        }                                                                      \
    }                                                                          \
    _Pragma("unroll")                                                          \
    for (int ns_ = 0; ns_ < 4; ++ns_) {                                        \
        int n_ = wc * 64 + ns_ * 16 + rl;                                      \
        bf_[ns_] = *(const bf16x8*)(bS_ + kcl * 2048 +                         \
                                    ((n_ * 16) ^ (kcl << 4)));                 \
    }                                                                          \
    __builtin_amdgcn_s_setprio(1);                                             \
    _Pragma("unroll")                                                          \
    for (int ms_ = 0; ms_ < 4; ++ms_)                                          \
        _Pragma("unroll")                                                      \
        for (int ns_ = 0; ns_ < 4; ++ns_)                                      \
            acc[ms_][ns_] = __builtin_amdgcn_mfma_f32_16x16x32_bf16(           \
                af_[ms_], bf_[ns_], acc[ms_][ns_], 0, 0, 0);                   \
    __builtin_amdgcn_s_setprio(0); } while (0)

// Epoch: wait -> barrier -> issue (slots proven free by the barrier) -> compute
#define EPOCH(kt_, IB_, IA_, NW_) do {                                         \
    VMW(NW_);                                                                  \
    __builtin_amdgcn_s_barrier();                                              \
    __builtin_amdgcn_sched_barrier(0);                                         \
    if (IB_) ISSUE_B((kt_) + 1, ((kt_) + 1) & 1);                              \
    if (IA_) ISSUE_A((kt_) + 2, ((kt_) + 2) % 3);                              \
    COMPUTE(kt_); } while (0)

    // ---- prologue: A(0)->slot0, B(0)->slot0, A(1)->slot1 (A1 newest) ----
    ISSUE_A(0, 0);
    ISSUE_B(0, 0);
    ISSUE_A(1, 1);

    // vmcnt ledger (issue-after-barrier): entering epoch t the FIFO is
    // [A(t):4, B(t):2, A(t+1):4]; vmcnt(4) keeps A(t+1), retires A(t)+B(t).
    EPOCH(0,  1, 1, 4);  EPOCH(1,  1, 1, 4);  EPOCH(2,  1, 1, 4);
    EPOCH(3,  1, 1, 4);  EPOCH(4,  1, 1, 4);  EPOCH(5,  1, 1, 4);
    EPOCH(6,  1, 1, 4);  EPOCH(7,  1, 1, 4);  EPOCH(8,  1, 1, 4);
    EPOCH(9,  1, 1, 4);  EPOCH(10, 1, 1, 4);  EPOCH(11, 1, 1, 4);
    EPOCH(12, 1, 1, 4);  EPOCH(13, 1, 1, 4);
    EPOCH(14, 1, 0, 4);   // issue B(15) only
    EPOCH(15, 0, 0, 0);   // drain A15,B15; compute-only

#undef EPOCH
#undef COMPUTE
#undef ISSUE_B
#undef ISSUE_A
#undef VMW

    // --- epilogue: partial score over this block's 128 n-cols ---
    float pc[4], vv[4];
    #pragma unroll
    for (int ns = 0; ns < 4; ++ns) {
        int ug = gy * 128 + wc * 64 + ns * 16 + rl;
        pc[ns] = phc[(size_t)b * UU + ug];
        vv[ns] = V[ug];
    }
    float pr[4][4];
    #pragma unroll
    for (int ms = 0; ms < 4; ++ms)
        #pragma unroll
        for (int rg = 0; rg < 4; ++rg) {
            float s = 0.f;
            #pragma unroll
            for (int ns = 0; ns < 4; ++ns)
                s += tanh_fast(acc[ms][ns][rg] + pc[ns]) * vv[ns];
            pr[ms][rg] = s;
        }
    #pragma unroll
    for (int off = 1; off < 16; off <<= 1)
        #pragma unroll
        for (int ms = 0; ms < 4; ++ms)
            #pragma unroll
            for (int rg = 0; rg < 4; ++rg)
                pr[ms][rg] += __shfl_xor(pr[ms][rg], off, 64);
    if ((lane & 15) == 0) {
        int rowg = lane >> 4;
        #pragma unroll
        for (int ms = 0; ms < 4; ++ms)
            #pragma unroll
            for (int rg = 0; rg < 4; ++rg)
                sRed[w][ms * 16 + rowg * 4 + rg] = pr[ms][rg];
    }
    __syncthreads();
    if (tid < 128) {
        int wrx = tid >> 6, ml = tid & 63;
        float v = sRed[2 * wrx][ml] + sRed[2 * wrx + 1][ml];
        part[(size_t)gy * MM + m0 + tid] = v;
    }
}

// ---------------------------------------------------------------------------
// Kernel 4: sum 4 partials -> softmax over T -> d_out attn region.
// ---------------------------------------------------------------------------
__global__ void k_softmax(const float* __restrict__ part, float* __restrict__ dout) {
    const int b = blockIdx.x, tid = threadIdx.x;   // 256 threads
    float* sc = dout + ATTN_OFF + (size_t)b * TT;
    float v[8];
    float mx = -3.4e38f;
    #pragma unroll
    for (int i = 0; i < 8; ++i) {
        int t = tid + 256 * i;
        size_t idx = (size_t)b * TT + t;
        v[i] = part[idx] + part[MM + idx] + part[2 * MM + idx] + part[3 * MM + idx];
        mx = fmaxf(mx, v[i]);
    }
    __shared__ float red[256];
    red[tid] = mx; __syncthreads();
    for (int s = 128; s >= 1; s >>= 1) {
        if (tid < s) red[tid] = fmaxf(red[tid], red[tid + s]);
        __syncthreads();
    }
    mx = red[0]; __syncthreads();
    float sum = 0.f;
    #pragma unroll
    for (int i = 0; i < 8; ++i) { v[i] = __expf(v[i] - mx); sum += v[i]; }
    red[tid] = sum; __syncthreads();
    for (int s = 128; s >= 1; s >>= 1) {
        if (tid < s) red[tid] += red[tid + s];
        __syncthreads();
    }
    float inv = 1.0f / red[0];
    #pragma unroll
    for (int i = 0; i < 8; ++i) sc[tid + 256 * i] = v[i] * inv;
}

// ---------------------------------------------------------------------------
// Kernel 5: context[b][d] = sum_t w[b][t] * feat[b][t][d]
// grid (64, 8); 256 threads = 16 d-quads (float4) x 16 t-subgroups.
// ---------------------------------------------------------------------------
__global__ void k_context(const float* __restrict__ feat, float* __restrict__ dout) {
    const int b = blockIdx.x, dc = blockIdx.y;
    const int dq = threadIdx.x & 15;          // float4 lane
    const int ty = threadIdx.x >> 4;          // 0..15
    const int d = dc * 64 + dq * 4;
    const float* wgt = dout + ATTN_OFF + (size_t)b * TT;
    const float* f = feat + (size_t)b * TT * DD + d;
    float4 acc = {0.f, 0.f, 0.f, 0.f};
    #pragma unroll 4
    for (int i = 0; i < TT / 16; ++i) {
        int t = i * 16 + ty;
        float wv = wgt[t];
        float4 fv = *(const float4*)(f + (size_t)t * DD);
        acc.x += wv * fv.x; acc.y += wv * fv.y;
        acc.z += wv * fv.z; acc.w += wv * fv.w;
    }
    __shared__ float4 red[16][16];
    red[ty][dq] = acc; __syncthreads();
    if (ty == 0) {
        float4 s = red[0][dq];
        #pragma unroll
        for (int k = 1; k < 16; ++k) {
            float4 r = red[k][dq];
            s.x += r.x; s.y += r.y; s.z += r.z; s.w += r.w;
        }
        *(float4*)(dout + (size_t)b * DD + d) = s;
    }
}

// ---------------------------------------------------------------------------
extern "C" void kernel_launch(void* const* d_in, const int* in_sizes, int n_in,
                              void* d_out, int out_size, void* d_ws, size_t ws_size,
                              hipStream_t stream) {
    (void)in_sizes; (void)n_in; (void)out_size; (void)ws_size;
    const float* feat   = (const float*)d_in[0];
    const float* hidden = (const float*)d_in[1];
    const float* W1     = (const float*)d_in[2];
    const float* b1     = (const float*)d_in[3];
    const float* W2     = (const float*)d_in[4];
    const float* b2     = (const float*)d_in[5];
    const float* V      = (const float*)d_in[6];
    // d_in[7] = bV : softmax-invariant constant, unused.

    // ws layout: [0,512K) W1T bf16; [512K,640K) phc f32; [640K,640K+2M) partials
    unsigned short* W1T = (unsigned short*)d_ws;
    float* phc  = (float*)((char*)d_ws + 512 * 1024);
    float* part = (float*)((char*)d_ws + 640 * 1024);
    float* out  = (float*)d_out;

    hipLaunchKernelGGL(k_w1t,     dim3(128),    dim3(256), 0, stream, W1, W1T);
    hipLaunchKernelGGL(k_phc,     dim3(64),     dim3(512), 0, stream, hidden, W2, b1, b2, phc);
    hipLaunchKernelGGL(k_score,   dim3(4096),   dim3(256), 0, stream, feat, W1T, phc, V, part);
    hipLaunchKernelGGL(k_softmax, dim3(64),     dim3(256), 0, stream, part, out);
    hipLaunchKernelGGL(k_context, dim3(64, 8),  dim3(256), 0, stream, feat, out);
}

// Round 11
// 200.601 us; speedup vs baseline: 1.4143x; 1.0788x over previous
//
#include <hip/hip_runtime.h>
#include <hip/hip_bf16.h>

// Problem constants (B=64, T=2048, D=512, U=512)
#define BB 64
#define TT 2048
#define DD 512
#define UU 512
#define MM (BB * TT)                 // 131072 rows
#define CTX_ELEMS (BB * DD)          // context region of d_out
#define ATTN_OFF  CTX_ELEMS          // attention region offset in d_out

typedef __bf16 bf16x8 __attribute__((ext_vector_type(8)));
typedef float  f32x4  __attribute__((ext_vector_type(4)));
typedef unsigned short u16x8 __attribute__((ext_vector_type(8)));
typedef unsigned int u32;

#define GLOBAL_AS __attribute__((address_space(1)))
#define LDS_AS    __attribute__((address_space(3)))

__device__ __forceinline__ unsigned short f2bf(float f) {
    union { float f; unsigned u; } x; x.f = f;
    unsigned r = x.u + 0x7fffu + ((x.u >> 16) & 1u);   // RNE
    return (unsigned short)(r >> 16);
}

__device__ __forceinline__ float tanh_fast(float x) {
    x = fminf(fmaxf(x, -10.f), 10.f);                  // avoid inf*0
    float e = __builtin_amdgcn_exp2f(x * 2.885390082f); // e^(2x)
    return (e - 1.0f) * __builtin_amdgcn_rcpf(e + 1.0f);
}

// ---------------------------------------------------------------------------
// Kernel 1: W1 [D][U] f32 -> W1T bf16, tiled layout (R2-proven):
//   tile ti = (nt*16 + kt), nt = u>>7, kt = d>>5  (8 KB per tile)
//   within tile: [kc(4)][n(128)][e(8)] : kc = (d&31)>>3, n = u&127, e = d&7
// ---------------------------------------------------------------------------
__global__ void k_w1t(const float* __restrict__ W1, unsigned short* __restrict__ W1T) {
    int gid = blockIdx.x * 256 + threadIdx.x;   // 32768 threads
    int u  = gid & 511;
    int dc = gid >> 9;                          // d-chunk of 8, 0..63
    int d0 = dc * 8;
    u16x8 pk;
    #pragma unroll
    for (int e = 0; e < 8; ++e)
        pk[e] = f2bf(W1[(size_t)(d0 + e) * UU + u]);
    int nt = u >> 7, n = u & 127;
    int kt = dc >> 2, kc = dc & 3;
    size_t off = ((size_t)(nt * 16 + kt) * 8192 + kc * 2048 + n * 16) / 2;
    *(u16x8*)(W1T + off) = pk;
}

// ---------------------------------------------------------------------------
// Kernel 2: phc[b][u] = b1[u] + b2[u] + hidden[b,:] @ W2[:,u]
// ---------------------------------------------------------------------------
__global__ void k_phc(const float* __restrict__ hidden, const float* __restrict__ W2,
                      const float* __restrict__ b1, const float* __restrict__ b2,
                      float* __restrict__ phc) {
    const int b = blockIdx.x;
    const int u = threadIdx.x;         // 512 threads
    const float* h = hidden + (size_t)b * DD;
    float acc = b1[u] + b2[u];
    #pragma unroll 8
    for (int d = 0; d < DD; ++d)
        acc += h[d] * W2[(size_t)d * UU + u];
    phc[(size_t)b * UU + u] = acc;
}

// ---------------------------------------------------------------------------
// Kernel 3: partial-score GEMM = R2's winning structure (128x128x32, 4 waves,
// reg-staged A with stage-time cvt, gload_lds B, 3 blocks/CU) with its two
// full-drain __syncthreads per step replaced by ONE raw barrier + counted
// vmcnt + cross-step B window (R10-proven issue-after-barrier ledger):
//   step kt: BAR -> issue A(kt+1)->regs(4), B(kt+2)->gload_lds ring3(2)
//            -> frag reads + 16 MFMA -> vmcnt(2) [retires B(kt+1)+A(kt+1),
//            keeps B(kt+2)] -> cvt+ds_write A(kt+1) -> lgkm0 -> BAR.
// FIFO invariant entering step kt: [B(kt+1):2]. B window ~1.3 steps (hidden);
// barrier count halved vs R2. Slot safety: writes target the slot whose
// readers finished before the barrier just crossed.
// LDS: sA 2x8K + sB 3x8K + sRed 1K = 41 KB -> 3 blocks/CU.
// Grid 4096 = 1024 gx x 4 gy, XCD-grouped (FETCH=1x verified R5-R10).
// ---------------------------------------------------------------------------
__launch_bounds__(256, 3)
__global__ void k_score(const float* __restrict__ feat,
                        const unsigned short* __restrict__ W1T,
                        const float* __restrict__ phc,
                        const float* __restrict__ V,
                        float* __restrict__ part) {
    __shared__ __align__(16) unsigned short sA[2][4096];   // 2 x 8 KB bf16
    __shared__ __align__(16) unsigned short sB[3][4096];   // 3 x 8 KB bf16
    __shared__ float sRed[4][64];

    const int tid   = threadIdx.x;
    const int lane  = tid & 63;
    const int w     = tid >> 6;               // wave 0..3
    const int wr    = w >> 1, wc = w & 1;     // 2M x 2N
    const int rl    = lane & 15;

    // XCD-aware decomposition (R2-proven)
    const int rb  = blockIdx.x;
    const int xcd = rb & 7;
    const int uu  = rb >> 3;
    const int gy  = uu & 3;
    const int gx  = xcd * 128 + (uu >> 2);
    const int m0  = gx * 128;
    const int b   = m0 >> 11;

    const char* bslab0 = (const char*)W1T + (size_t)gy * 16 * 8192;

    // A staging: thread covers row r = tid>>1 (0..127), k-half h = tid&1
    const int r = tid >> 1;
    const int h = tid & 1;
    const char* fA = (const char*)feat + (size_t)(m0 + r) * 2048 + h * 64;

    f32x4 rS0, rS1, rS2, rS3;

    f32x4 acc[4][4];
    #pragma unroll
    for (int i = 0; i < 4; ++i)
        #pragma unroll
        for (int j = 0; j < 4; ++j)
            acc[i][j] = (f32x4){0.f, 0.f, 0.f, 0.f};

#define VMW2()  asm volatile("s_waitcnt vmcnt(2)" ::: "memory")
#define VMW4()  asm volatile("s_waitcnt vmcnt(4)" ::: "memory")
#define VMW0()  asm volatile("s_waitcnt vmcnt(0)" ::: "memory")
#define LGKM0() asm volatile("s_waitcnt lgkmcnt(0)" ::: "memory")
#define SBAR()  __builtin_amdgcn_s_barrier()
#define SCB()   __builtin_amdgcn_sched_barrier(0)

#define ISSUE_A(kt_) do {                                                     \
    const char* s_ = fA + (kt_) * 128;                                        \
    rS0 = *(const f32x4*)(s_);                                                \
    rS1 = *(const f32x4*)(s_ + 16);                                           \
    rS2 = *(const f32x4*)(s_ + 32);                                           \
    rS3 = *(const f32x4*)(s_ + 48); } while (0)

#define ISSUE_B(kt_, s_) do {                                                 \
    const char* bs_ = bslab0 + (size_t)(kt_) * 8192;                          \
    _Pragma("unroll")                                                         \
    for (int p_ = 0; p_ < 2; ++p_) {                                          \
        const char* src_ = bs_ + (size_t)(p_ * 256 + tid) * 16;               \
        char* dst_ = (char*)&sB[s_][0] + (size_t)(p_ * 256 + (tid & ~63)) * 16;\
        __builtin_amdgcn_global_load_lds((const GLOBAL_AS u32*)src_,          \
                                         (LDS_AS u32*)dst_, 16, 0, 0);        \
    } } while (0)

#define WRITE_A(buf_) do {                                                    \
    bf16x8 q0_, q1_;                                                          \
    _Pragma("unroll")                                                         \
    for (int j_ = 0; j_ < 4; ++j_) {                                          \
        q0_[j_] = (__bf16)rS0[j_]; q0_[4 + j_] = (__bf16)rS1[j_];             \
        q1_[j_] = (__bf16)rS2[j_]; q1_[4 + j_] = (__bf16)rS3[j_];             \
    }                                                                         \
    *(bf16x8*)((char*)&sA[buf_][0] + (2 * h) * 2048 + r * 16) = q0_;          \
    *(bf16x8*)((char*)&sA[buf_][0] + (2 * h + 1) * 2048 + r * 16) = q1_; } while (0)

#define FRAG_MFMA(ab_, bb_) do {                                              \
    const int kc_ = lane >> 4;                                                \
    bf16x8 af_[4], bf_[4];                                                    \
    _Pragma("unroll")                                                         \
    for (int ns_ = 0; ns_ < 4; ++ns_)                                         \
        bf_[ns_] = *(const bf16x8*)((const char*)&sB[bb_][0] + kc_ * 2048 +   \
                                    (wc * 64 + ns_ * 16 + rl) * 16);          \
    _Pragma("unroll")                                                         \
    for (int ms_ = 0; ms_ < 4; ++ms_)                                         \
        af_[ms_] = *(const bf16x8*)((const char*)&sA[ab_][0] + kc_ * 2048 +   \
                                    (wr * 64 + ms_ * 16 + rl) * 16);          \
    __builtin_amdgcn_s_setprio(1);                                            \
    _Pragma("unroll")                                                         \
    for (int ms_ = 0; ms_ < 4; ++ms_)                                         \
        _Pragma("unroll")                                                     \
        for (int ns_ = 0; ns_ < 4; ++ns_)                                     \
            acc[ms_][ns_] = __builtin_amdgcn_mfma_f32_16x16x32_bf16(          \
                af_[ms_], bf_[ns_], acc[ms_][ns_], 0, 0, 0);                  \
    __builtin_amdgcn_s_setprio(0); } while (0)

// Steady step kt (issues A(kt+1), B(kt+2)); entering FIFO = [B(kt+1):2]
#define STEP(kt_) do {                                                        \
    ISSUE_A((kt_) + 1);                                                       \
    SCB();                                                                    \
    ISSUE_B((kt_) + 2, ((kt_) + 2) % 3);                                      \
    FRAG_MFMA((kt_) & 1, (kt_) % 3);                                          \
    VMW2();                  /* retire B(kt+1)+A(kt+1); keep B(kt+2) */       \
    WRITE_A(((kt_) + 1) & 1);                                                 \
    LGKM0();                                                                  \
    SBAR(); } while (0)

    // ---- prologue ----
    ISSUE_A(0);          // A0: 4 loads (oldest)
    SCB();
    ISSUE_B(0, 0);       // B0: 2
    ISSUE_B(1, 1);       // B1: 2
    VMW4();              // retire A0; keep B0,B1
    WRITE_A(0);
    VMW2();              // retire B0 (sB[0] ready); keep B1
    LGKM0();
    SBAR();
    // invariant entering step 0: outstanding = [B1:2]

    STEP(0);  STEP(1);  STEP(2);  STEP(3);
    STEP(4);  STEP(5);  STEP(6);  STEP(7);
    STEP(8);  STEP(9);  STEP(10); STEP(11);
    STEP(12); STEP(13);
    {   // step 14: issue A(15) only; drain everything
        ISSUE_A(15);
        FRAG_MFMA(14 & 1, 14 % 3);
        VMW0();          // retire B(15) + A(15)
        WRITE_A(15 & 1);
        LGKM0();
        SBAR();
    }
    {   // step 15: compute only
        FRAG_MFMA(15 & 1, 15 % 3);
    }

#undef STEP
#undef FRAG_MFMA
#undef WRITE_A
#undef ISSUE_B
#undef ISSUE_A
#undef VMW2
#undef VMW4
#undef VMW0
#undef LGKM0
#undef SBAR
#undef SCB

    // --- epilogue: partial score over this block's 128 n-cols ---
    float pc[4], vv[4];
    #pragma unroll
    for (int ns = 0; ns < 4; ++ns) {
        int ug = gy * 128 + wc * 64 + ns * 16 + rl;
        pc[ns] = phc[(size_t)b * UU + ug];
        vv[ns] = V[ug];
    }
    float pr[4][4];
    #pragma unroll
    for (int ms = 0; ms < 4; ++ms)
        #pragma unroll
        for (int rg = 0; rg < 4; ++rg) {
            float s = 0.f;
            #pragma unroll
            for (int ns = 0; ns < 4; ++ns)
                s += tanh_fast(acc[ms][ns][rg] + pc[ns]) * vv[ns];
            pr[ms][rg] = s;
        }
    #pragma unroll
    for (int off = 1; off < 16; off <<= 1)
        #pragma unroll
        for (int ms = 0; ms < 4; ++ms)
            #pragma unroll
            for (int rg = 0; rg < 4; ++rg)
                pr[ms][rg] += __shfl_xor(pr[ms][rg], off, 64);
    if ((lane & 15) == 0) {
        int rowg = lane >> 4;
        #pragma unroll
        for (int ms = 0; ms < 4; ++ms)
            #pragma unroll
            for (int rg = 0; rg < 4; ++rg)
                sRed[w][ms * 16 + rowg * 4 + rg] = pr[ms][rg];
    }
    __syncthreads();
    if (tid < 128) {
        int wrx = tid >> 6, ml = tid & 63;
        float v = sRed[2 * wrx][ml] + sRed[2 * wrx + 1][ml];
        part[(size_t)gy * MM + m0 + tid] = v;
    }
}

// ---------------------------------------------------------------------------
// Kernel 4: sum 4 partials -> softmax over T -> d_out attn region.
// ---------------------------------------------------------------------------
__global__ void k_softmax(const float* __restrict__ part, float* __restrict__ dout) {
    const int b = blockIdx.x, tid = threadIdx.x;   // 256 threads
    float* sc = dout + ATTN_OFF + (size_t)b * TT;
    float v[8];
    float mx = -3.4e38f;
    #pragma unroll
    for (int i = 0; i < 8; ++i) {
        int t = tid + 256 * i;
        size_t idx = (size_t)b * TT + t;
        v[i] = part[idx] + part[MM + idx] + part[2 * MM + idx] + part[3 * MM + idx];
        mx = fmaxf(mx, v[i]);
    }
    __shared__ float red[256];
    red[tid] = mx; __syncthreads();
    for (int s = 128; s >= 1; s >>= 1) {
        if (tid < s) red[tid] = fmaxf(red[tid], red[tid + s]);
        __syncthreads();
    }
    mx = red[0]; __syncthreads();
    float sum = 0.f;
    #pragma unroll
    for (int i = 0; i < 8; ++i) { v[i] = __expf(v[i] - mx); sum += v[i]; }
    red[tid] = sum; __syncthreads();
    for (int s = 128; s >= 1; s >>= 1) {
        if (tid < s) red[tid] += red[tid + s];
        __syncthreads();
    }
    float inv = 1.0f / red[0];
    #pragma unroll
    for (int i = 0; i < 8; ++i) sc[tid + 256 * i] = v[i] * inv;
}

// ---------------------------------------------------------------------------
// Kernel 5: context[b][d] = sum_t w[b][t] * feat[b][t][d]
// grid (64, 8); 256 threads = 16 d-quads (float4) x 16 t-subgroups.
// ---------------------------------------------------------------------------
__global__ void k_context(const float* __restrict__ feat, float* __restrict__ dout) {
    const int b = blockIdx.x, dc = blockIdx.y;
    const int dq = threadIdx.x & 15;          // float4 lane
    const int ty = threadIdx.x >> 4;          // 0..15
    const int d = dc * 64 + dq * 4;
    const float* wgt = dout + ATTN_OFF + (size_t)b * TT;
    const float* f = feat + (size_t)b * TT * DD + d;
    float4 acc = {0.f, 0.f, 0.f, 0.f};
    #pragma unroll 4
    for (int i = 0; i < TT / 16; ++i) {
        int t = i * 16 + ty;
        float wv = wgt[t];
        float4 fv = *(const float4*)(f + (size_t)t * DD);
        acc.x += wv * fv.x; acc.y += wv * fv.y;
        acc.z += wv * fv.z; acc.w += wv * fv.w;
    }
    __shared__ float4 red[16][16];
    red[ty][dq] = acc; __syncthreads();
    if (ty == 0) {
        float4 s = red[0][dq];
        #pragma unroll
        for (int k = 1; k < 16; ++k) {
            float4 r = red[k][dq];
            s.x += r.x; s.y += r.y; s.z += r.z; s.w += r.w;
        }
        *(float4*)(dout + (size_t)b * DD + d) = s;
    }
}

// ---------------------------------------------------------------------------
extern "C" void kernel_launch(void* const* d_in, const int* in_sizes, int n_in,
                              void* d_out, int out_size, void* d_ws, size_t ws_size,
                              hipStream_t stream) {
    (void)in_sizes; (void)n_in; (void)out_size; (void)ws_size;
    const float* feat   = (const float*)d_in[0];
    const float* hidden = (const float*)d_in[1];
    const float* W1     = (const float*)d_in[2];
    const float* b1     = (const float*)d_in[3];
    const float* W2     = (const float*)d_in[4];
    const float* b2     = (const float*)d_in[5];
    const float* V      = (const float*)d_in[6];
    // d_in[7] = bV : softmax-invariant constant, unused.

    // ws layout: [0,512K) W1T bf16; [512K,640K) phc f32; [640K,640K+2M) partials
    unsigned short* W1T = (unsigned short*)d_ws;
    float* phc  = (float*)((char*)d_ws + 512 * 1024);
    float* part = (float*)((char*)d_ws + 640 * 1024);
    float* out  = (float*)d_out;

    hipLaunchKernelGGL(k_w1t,     dim3(128),    dim3(256), 0, stream, W1, W1T);
    hipLaunchKernelGGL(k_phc,     dim3(64),     dim3(512), 0, stream, hidden, W2, b1, b2, phc);
    hipLaunchKernelGGL(k_score,   dim3(4096),   dim3(256), 0, stream, feat, W1T, phc, V, part);
    hipLaunchKernelGGL(k_softmax, dim3(64),     dim3(256), 0, stream, part, out);
    hipLaunchKernelGGL(k_context, dim3(64, 8),  dim3(256), 0, stream, feat, out);
}